// Round 3
// baseline (3388.589 us; speedup 1.0000x reference)
//
#include <hip/hip_runtime.h>

constexpr int B = 4, T = 8, N = 4096, C0 = 64, C1 = 128;
constexpr int M = 1024, KNN = 32;

template <int CTRL>
__device__ __forceinline__ float dppf(float x) {
  return __int_as_float(__builtin_amdgcn_update_dpp(0, __float_as_int(x), CTRL, 0xF, 0xF, true));
}
template <int CTRL>
__device__ __forceinline__ int dppi(int x) {
  return __builtin_amdgcn_update_dpp(0, x, CTRL, 0xF, 0xF, true);
}

// ---------------- transpose features (B,T,64,4096) -> featT (B,T,4096,64) ----
__global__ __launch_bounds__(256) void transpose_kernel(const float* __restrict__ f,
                                                        float* __restrict__ ft) {
  __shared__ float tile[64][65];
  int bt = blockIdx.y;
  int n0 = blockIdx.x * 64;
  const float* src = f + (size_t)bt * C0 * N;
  int tx = threadIdx.x & 63, ty = threadIdx.x >> 6;
  for (int r = ty; r < 64; r += 4)
    tile[r][tx] = src[(size_t)r * N + n0 + tx];
  __syncthreads();
  float* dst = ft + ((size_t)bt * N + n0) * 64;
  for (int r = ty; r < 64; r += 4)
    dst[(size_t)r * 64 + tx] = tile[tx][r];
}

// ---------------- prep: WfT[j][c] = Wf[c][j] --------------------------------
__global__ __launch_bounds__(256) void prep_wft(const float* __restrict__ Wf,
                                                float* __restrict__ WfT) {
  int t = blockIdx.x * 256 + threadIdx.x;
  if (t < 64 * 64) WfT[t] = Wf[(t & 63) * 64 + (t >> 6)];
}

// ---------------- furthest point sampling: one block (4 waves) per (b,t) ----
__global__ __launch_bounds__(256) void fps_kernel(const float* __restrict__ xyz,
                                                  float* __restrict__ out_xyz) {
  __shared__ float xs[N], ys[N], zs[N];
  __shared__ float rv[2][4];
  __shared__ int ri[2][4];
  int bt = blockIdx.x;
  const float* p = xyz + (size_t)bt * N * 3;
  int tid = threadIdx.x;
  int lane = tid & 63, w = tid >> 6;
  for (int i = tid; i < N; i += 256) {
    xs[i] = p[i * 3 + 0];
    ys[i] = p[i * 3 + 1];
    zs[i] = p[i * 3 + 2];
  }
  __syncthreads();
  float X[16], Y[16], Z[16], D[16];
#pragma unroll
  for (int j = 0; j < 16; ++j) {
    X[j] = xs[tid * 16 + j];
    Y[j] = ys[tid * 16 + j];
    Z[j] = zs[tid * 16 + j];
    D[j] = 1e10f;
  }
  if (tid == 0) {
    out_xyz[(size_t)bt * M * 3 + 0] = xs[0];
    out_xyz[(size_t)bt * M * 3 + 1] = ys[0];
    out_xyz[(size_t)bt * M * 3 + 2] = zs[0];
  }
  int lidx = 0;
  for (int s = 1; s < M; ++s) {
    float lx = xs[lidx], ly = ys[lidx], lz = zs[lidx];
    float bv = -1.0f;
    int bi = 0x7fffffff;
#pragma unroll
    for (int j = 0; j < 16; ++j) {
      float dx = __fsub_rn(X[j], lx);
      float dy = __fsub_rn(Y[j], ly);
      float dz = __fsub_rn(Z[j], lz);
      float d = __fadd_rn(__fadd_rn(__fmul_rn(dx, dx), __fmul_rn(dy, dy)), __fmul_rn(dz, dz));
      float nd = fminf(D[j], d);
      D[j] = nd;
      if (nd > bv) { bv = nd; bi = tid * 16 + j; }
    }
    // in-wave (val,idx) argmax reduce: DPP hops (VALU) + 2 shfl hops.
    // After quad xor1,xor2 quads are uniform; half-mirror merges quads within 8,
    // mirror merges 8s within 16, then xor16/xor32. Tie-break: smaller idx wins.
#define FPS_MERGE(OV, OI) if ((OV) > bv || ((OV) == bv && (OI) < bi)) { bv = (OV); bi = (OI); }
    { float ov = dppf<0xB1>(bv);  int oi = dppi<0xB1>(bi);  FPS_MERGE(ov, oi) }
    { float ov = dppf<0x4E>(bv);  int oi = dppi<0x4E>(bi);  FPS_MERGE(ov, oi) }
    { float ov = dppf<0x141>(bv); int oi = dppi<0x141>(bi); FPS_MERGE(ov, oi) }
    { float ov = dppf<0x140>(bv); int oi = dppi<0x140>(bi); FPS_MERGE(ov, oi) }
    { float ov = __shfl_xor(bv, 16, 64); int oi = __shfl_xor(bi, 16, 64); FPS_MERGE(ov, oi) }
    { float ov = __shfl_xor(bv, 32, 64); int oi = __shfl_xor(bi, 32, 64); FPS_MERGE(ov, oi) }
#undef FPS_MERGE
    int buf = s & 1;
    if (lane == 0) { rv[buf][w] = bv; ri[buf][w] = bi; }
    __syncthreads();
    float fv = rv[buf][0];
    int fi = ri[buf][0];
#pragma unroll
    for (int q = 1; q < 4; ++q) {
      float ov = rv[buf][q];
      int oi = ri[buf][q];
      if (ov > fv || (ov == fv && oi < fi)) { fv = ov; fi = oi; }
    }
    lidx = fi;
    if (tid == 0) {
      out_xyz[((size_t)(bt * M + s)) * 3 + 0] = xs[lidx];
      out_xyz[((size_t)(bt * M + s)) * 3 + 1] = ys[lidx];
      out_xyz[((size_t)(bt * M + s)) * 3 + 2] = zs[lidx];
    }
  }
}

// ---------------- ball query: one wave per (b,t,di,m) -----------------------
__global__ __launch_bounds__(256) void ballq_kernel(const float* __restrict__ xyz,
                                                    const float* __restrict__ anchors,
                                                    int* __restrict__ idxbuf) {
  const float R2 = 0.04f;
  int w = threadIdx.x >> 6, lane = threadIdx.x & 63;
  int q = blockIdx.x * 4 + w;
  int m = q & (M - 1);
  int di = (q >> 10) % 3;
  int bt = q / (M * 3);
  int b = bt >> 3, t = bt & 7;
  int srct = t + di - 1;
  srct = srct < 0 ? 0 : (srct > 7 ? 7 : srct);
  const float* anc = anchors + ((size_t)(bt * M + m)) * 3;
  float ax = anc[0], ay = anc[1], az = anc[2];
  const float* pts = xyz + ((size_t)(b * T + srct)) * N * 3;
  int* outp = idxbuf + (size_t)q * KNN;
  int cnt = 0, first = 0;
  for (int c = 0; c < N / 64 && cnt < KNN; ++c) {
    int pi = c * 64 + lane;
    const float* pp = pts + (size_t)pi * 3;
    float dx = __fsub_rn(ax, pp[0]);
    float dy = __fsub_rn(ay, pp[1]);
    float dz = __fsub_rn(az, pp[2]);
    float d2 = __fadd_rn(__fadd_rn(__fmul_rn(dx, dx), __fmul_rn(dy, dy)), __fmul_rn(dz, dz));
    bool hit = d2 < R2;
    unsigned long long mask = __ballot(hit);
    if (cnt == 0 && mask) first = c * 64 + (int)__builtin_ctzll(mask);
    int prefix = (int)__popcll(mask & ((1ull << lane) - 1ull));
    int slot = cnt + prefix;
    if (hit && slot < KNN) outp[slot] = pi;
    cnt += (int)__popcll(mask);
  }
  int cntK = cnt < KNN ? cnt : KNN;
  int fill = (cnt == 0) ? 0 : first;
  if (lane < KNN && lane >= cntK) outp[lane] = fill;
}

// ---------------- fused grouping + MLP, lane = neighbor k -------------------
// 1 wave per block, 2 anchors per wave (lanes 0-31 / 32-63), lane = k.
// Each lane stages its own neighbor's 64-ch feature row in LDS (stride 65,
// runtime-indexable), both layers are per-lane dots with s_load'd weights.
__global__ __launch_bounds__(64, 2) void mlp_kernel(const float* __restrict__ xyz,
                                                    const float* __restrict__ featT,
                                                    const float* __restrict__ Wd,
                                                    const float* __restrict__ WfT,
                                                    const float* __restrict__ W1,
                                                    const float* __restrict__ anchors,
                                                    const int* __restrict__ idxbuf,
                                                    float* __restrict__ out_feats) {
  __shared__ float fbuf[64 * 65];
  __shared__ float accb[3][2][128];
  int lane = threadIdx.x;
  int bt = blockIdx.x >> 9;            // 16384 blocks
  int m0 = (blockIdx.x & 511) * 2;
  int b = bt >> 3, t = bt & 7;
  int alocal = lane >> 5, k = lane & 31;
  int m = m0 + alocal;
  float ax = anchors[((size_t)(bt * M + m)) * 3 + 0];
  float ay = anchors[((size_t)(bt * M + m)) * 3 + 1];
  float az = anchors[((size_t)(bt * M + m)) * 3 + 2];
  float* myrow = &fbuf[lane * 65];
  for (int di = 0; di < 3; ++di) {
    int srct = t + di - 1;
    srct = srct < 0 ? 0 : (srct > 7 ? 7 : srct);
    const float* pts = xyz + ((size_t)(b * T + srct)) * N * 3;
    const float* ft = featT + ((size_t)(b * T + srct)) * N * 64;
    int n = idxbuf[((size_t)(bt * 3 + di) * M + m) * KNN + k];
    // drain previous iteration's LDS reads before overwriting the row
    asm volatile("s_waitcnt lgkmcnt(0)" ::: "memory");
    const float* gp = ft + (size_t)n * 64;
#pragma unroll
    for (int c = 0; c < 64; c += 4) {
      float4 v = *(const float4*)&gp[c];
      myrow[c + 0] = v.x; myrow[c + 1] = v.y; myrow[c + 2] = v.z; myrow[c + 3] = v.w;
    }
    float px = pts[n * 3 + 0], py = pts[n * 3 + 1], pz = pts[n * 3 + 2];
    float dx = px - ax, dy = py - ay, dz = pz - az, tv = (float)(di - 1);
    // dfeat: relu(Wd @ [dx,dy,dz,tv]) -> h
    float h[64];
#pragma unroll
    for (int c = 0; c < 64; ++c) {
      float dd = fmaf(dx, Wd[c * 4 + 0],
                 fmaf(dy, Wd[c * 4 + 1], fmaf(dz, Wd[c * 4 + 2], tv * Wd[c * 4 + 3])));
      h[c] = fmaxf(dd, 0.f);
    }
    // layer 1: ff[c] = sum_j WfT[j][c] * f_j   (weights via scalar loads)
    float ff[64];
#pragma unroll
    for (int c = 0; c < 64; ++c) ff[c] = 0.f;
#pragma unroll 2
    for (int j = 0; j < 64; ++j) {
      float fj = myrow[j];
      const float* wr = WfT + j * 64;
#pragma unroll
      for (int c = 0; c < 64; ++c) ff[c] = fmaf(fj, wr[c], ff[c]);
    }
#pragma unroll
    for (int c = 0; c < 64; ++c) h[c] = fmaxf(ff[c], 0.f) + h[c];
    // layer 2 + relu + max over the 32-lane k-group (DPP + one shfl16)
#pragma unroll 2
    for (int j = 0; j < 128; ++j) {
      const float* wr = W1 + j * 64;
      float o0 = 0.f, o1 = 0.f, o2 = 0.f, o3 = 0.f;
#pragma unroll
      for (int c = 0; c < 64; c += 4) {
        o0 = fmaf(h[c + 0], wr[c + 0], o0);
        o1 = fmaf(h[c + 1], wr[c + 1], o1);
        o2 = fmaf(h[c + 2], wr[c + 2], o2);
        o3 = fmaf(h[c + 3], wr[c + 3], o3);
      }
      float o = fmaxf((o0 + o1) + (o2 + o3), 0.f);
      o = fmaxf(o, dppf<0xB1>(o));
      o = fmaxf(o, dppf<0x4E>(o));
      o = fmaxf(o, dppf<0x141>(o));
      o = fmaxf(o, dppf<0x140>(o));
      o = fmaxf(o, __shfl_xor(o, 16, 64));
      if (k == 0) accb[di][alocal][j] = o;
    }
  }
  asm volatile("s_waitcnt lgkmcnt(0)" ::: "memory");
#pragma unroll
  for (int rep = 0; rep < 2; ++rep) {
    int j = lane + rep * 64;
    float s0 = (accb[0][0][j] + accb[1][0][j]) + accb[2][0][j];
    float s1 = (accb[0][1][j] + accb[1][1][j]) + accb[2][1][j];
    float2 v = make_float2(s0, s1);
    *(float2*)&out_feats[((size_t)(bt * C1 + j)) * M + m0] = v;
  }
}

extern "C" void kernel_launch(void* const* d_in, const int* in_sizes, int n_in,
                              void* d_out, int out_size, void* d_ws, size_t ws_size,
                              hipStream_t stream) {
  const float* xyzs = (const float*)d_in[0];
  const float* feats = (const float*)d_in[1];
  const float* Wd = (const float*)d_in[2];
  const float* Wf = (const float*)d_in[3];
  const float* W1 = (const float*)d_in[4];
  float* out_xyz = (float*)d_out;                           // (B,8,M,3)
  float* out_feats = (float*)d_out + (size_t)B * T * M * 3; // (B,8,C1,M)
  char* ws = (char*)d_ws;
  float* featT = (float*)ws;                                   // 33.55 MB
  int* idxbuf = (int*)(ws + (size_t)B * T * N * 64 * 4);       // 12.58 MB
  float* WfT = (float*)(ws + (size_t)B * T * N * 64 * 4 + (size_t)B * T * 3 * M * KNN * 4);
  transpose_kernel<<<dim3(N / 64, B * T), 256, 0, stream>>>(feats, featT);
  prep_wft<<<16, 256, 0, stream>>>(Wf, WfT);
  fps_kernel<<<B * T, 256, 0, stream>>>(xyzs, out_xyz);
  ballq_kernel<<<(B * T * 3 * M) / 4, 256, 0, stream>>>(xyzs, out_xyz, idxbuf);
  mlp_kernel<<<(size_t)B * T * M / 2, 64, 0, stream>>>(xyzs, featT, Wd, WfT, W1, out_xyz,
                                                       idxbuf, out_feats);
}

// Round 4
// 1675.701 us; speedup vs baseline: 2.0222x; 2.0222x over previous
//
#include <hip/hip_runtime.h>

constexpr int B = 4, T = 8, N = 4096, C0 = 64, C1 = 128;
constexpr int M = 1024, KNN = 32;

typedef __attribute__((ext_vector_type(8))) short short8;
typedef __attribute__((ext_vector_type(4))) float f32x4;

__device__ __forceinline__ unsigned short f2bf(float x) {
  unsigned u = __float_as_uint(x);
  u = u + 0x7FFFu + ((u >> 16) & 1u);
  return (unsigned short)(u >> 16);
}
__device__ __forceinline__ float bf2f(unsigned short h) {
  return __uint_as_float((unsigned)h << 16);
}

template <int CTRL>
__device__ __forceinline__ float dppf(float x) {
  return __int_as_float(__builtin_amdgcn_update_dpp(0, __float_as_int(x), CTRL, 0xF, 0xF, true));
}
template <int CTRL>
__device__ __forceinline__ int dppi(int x) {
  return __builtin_amdgcn_update_dpp(0, x, CTRL, 0xF, 0xF, true);
}

// ---------------- prep: WfT[c][o] = Wf[o][c] --------------------------------
__global__ __launch_bounds__(256) void prep_wft(const float* __restrict__ Wf,
                                                float* __restrict__ WfT) {
  int t = blockIdx.x * 256 + threadIdx.x;
  if (t < 64 * 64) WfT[t] = Wf[(t & 63) * 64 + (t >> 6)];
}

// ---------------- prep: W1 -> MFMA A-fragment-ordered bf16 hi/lo ------------
// frag (kt,mt), lane l, slot j holds W1[mt*16 + (l&15)][kt*32 + (l>>4)*8 + j]
__global__ __launch_bounds__(256) void prep_w1frag(const float* __restrict__ W1,
                                                   unsigned short* __restrict__ w1hi,
                                                   unsigned short* __restrict__ w1lo) {
  int t = blockIdx.x * 256 + threadIdx.x;
  if (t >= 8192) return;
  int j = t & 7, lane = (t >> 3) & 63, mt = (t >> 9) & 7, kt = t >> 12;
  int row = mt * 16 + (lane & 15);
  int k = kt * 32 + (lane >> 4) * 8 + j;
  float v = W1[row * 64 + k];
  unsigned short hi = f2bf(v);
  w1hi[t] = hi;
  w1lo[t] = f2bf(v - bf2f(hi));
}

// ---------------- RFF[n] = relu(Wf @ f_n), fused with transpose -------------
// block: 64 points; stage features tile [c][n] in LDS, compute 16 outputs per
// thread with wave-uniform WfT rows (scalar loads), transpose via LDS, write
// RFF[n][o] coalesced.
__global__ __launch_bounds__(256) void rff_kernel(const float* __restrict__ f,
                                                  const float* __restrict__ WfT,
                                                  float* __restrict__ RFF) {
  __shared__ float tile[64][65];
  int bt = blockIdx.y;
  int n0 = blockIdx.x * 64;
  const float* src = f + (size_t)bt * C0 * N;
  int tx = threadIdx.x & 63, ty = threadIdx.x >> 6;
  for (int r = ty; r < 64; r += 4)
    tile[r][tx] = src[(size_t)r * N + n0 + tx];
  __syncthreads();
  float acc[16];
#pragma unroll
  for (int oo = 0; oo < 16; ++oo) acc[oo] = 0.f;
  int obase = ty * 16;  // wave-uniform
#pragma unroll 4
  for (int c = 0; c < 64; ++c) {
    float fv = tile[c][tx];
    const float* wr = WfT + c * 64 + obase;  // uniform -> s_load
#pragma unroll
    for (int oo = 0; oo < 16; ++oo) acc[oo] = fmaf(fv, wr[oo], acc[oo]);
  }
  __syncthreads();
#pragma unroll
  for (int oo = 0; oo < 16; ++oo) tile[obase + oo][tx] = fmaxf(acc[oo], 0.f);
  __syncthreads();
  float* dst = RFF + ((size_t)bt * N + n0) * 64;
  for (int r = ty; r < 64; r += 4)
    dst[(size_t)r * 64 + tx] = tile[tx][r];
}

// ---------------- furthest point sampling: one block (4 waves) per (b,t) ----
__global__ __launch_bounds__(256) void fps_kernel(const float* __restrict__ xyz,
                                                  float* __restrict__ out_xyz) {
  __shared__ float xs[N], ys[N], zs[N];
  __shared__ float rv[2][4];
  __shared__ int ri[2][4];
  int bt = blockIdx.x;
  const float* p = xyz + (size_t)bt * N * 3;
  int tid = threadIdx.x;
  int lane = tid & 63, w = tid >> 6;
  for (int i = tid; i < N; i += 256) {
    xs[i] = p[i * 3 + 0];
    ys[i] = p[i * 3 + 1];
    zs[i] = p[i * 3 + 2];
  }
  __syncthreads();
  float X[16], Y[16], Z[16], D[16];
#pragma unroll
  for (int j = 0; j < 16; ++j) {
    X[j] = xs[tid * 16 + j];
    Y[j] = ys[tid * 16 + j];
    Z[j] = zs[tid * 16 + j];
    D[j] = 1e10f;
  }
  if (tid == 0) {
    out_xyz[(size_t)bt * M * 3 + 0] = xs[0];
    out_xyz[(size_t)bt * M * 3 + 1] = ys[0];
    out_xyz[(size_t)bt * M * 3 + 2] = zs[0];
  }
  int lidx = 0;
  for (int s = 1; s < M; ++s) {
    float lx = xs[lidx], ly = ys[lidx], lz = zs[lidx];
    float bv = -1.0f;
    int bi = 0x7fffffff;
#pragma unroll
    for (int j = 0; j < 16; ++j) {
      float dx = __fsub_rn(X[j], lx);
      float dy = __fsub_rn(Y[j], ly);
      float dz = __fsub_rn(Z[j], lz);
      float d = __fadd_rn(__fadd_rn(__fmul_rn(dx, dx), __fmul_rn(dy, dy)), __fmul_rn(dz, dz));
      float nd = fminf(D[j], d);
      D[j] = nd;
      if (nd > bv) { bv = nd; bi = tid * 16 + j; }
    }
#define FPS_MERGE(OV, OI) if ((OV) > bv || ((OV) == bv && (OI) < bi)) { bv = (OV); bi = (OI); }
    { float ov = dppf<0xB1>(bv);  int oi = dppi<0xB1>(bi);  FPS_MERGE(ov, oi) }
    { float ov = dppf<0x4E>(bv);  int oi = dppi<0x4E>(bi);  FPS_MERGE(ov, oi) }
    { float ov = dppf<0x141>(bv); int oi = dppi<0x141>(bi); FPS_MERGE(ov, oi) }
    { float ov = dppf<0x140>(bv); int oi = dppi<0x140>(bi); FPS_MERGE(ov, oi) }
    { float ov = __shfl_xor(bv, 16, 64); int oi = __shfl_xor(bi, 16, 64); FPS_MERGE(ov, oi) }
    { float ov = __shfl_xor(bv, 32, 64); int oi = __shfl_xor(bi, 32, 64); FPS_MERGE(ov, oi) }
#undef FPS_MERGE
    int buf = s & 1;
    if (lane == 0) { rv[buf][w] = bv; ri[buf][w] = bi; }
    __syncthreads();
    float fv = rv[buf][0];
    int fi = ri[buf][0];
#pragma unroll
    for (int q = 1; q < 4; ++q) {
      float ov = rv[buf][q];
      int oi = ri[buf][q];
      if (ov > fv || (ov == fv && oi < fi)) { fv = ov; fi = oi; }
    }
    lidx = fi;
    if (tid == 0) {
      out_xyz[((size_t)(bt * M + s)) * 3 + 0] = xs[lidx];
      out_xyz[((size_t)(bt * M + s)) * 3 + 1] = ys[lidx];
      out_xyz[((size_t)(bt * M + s)) * 3 + 2] = zs[lidx];
    }
  }
}

// ---------------- ball query: one wave per (b,t,di,m) -----------------------
__global__ __launch_bounds__(256) void ballq_kernel(const float* __restrict__ xyz,
                                                    const float* __restrict__ anchors,
                                                    int* __restrict__ idxbuf) {
  const float R2 = 0.04f;
  int w = threadIdx.x >> 6, lane = threadIdx.x & 63;
  int q = blockIdx.x * 4 + w;
  int m = q & (M - 1);
  int di = (q >> 10) % 3;
  int bt = q / (M * 3);
  int b = bt >> 3, t = bt & 7;
  int srct = t + di - 1;
  srct = srct < 0 ? 0 : (srct > 7 ? 7 : srct);
  const float* anc = anchors + ((size_t)(bt * M + m)) * 3;
  float ax = anc[0], ay = anc[1], az = anc[2];
  const float* pts = xyz + ((size_t)(b * T + srct)) * N * 3;
  int* outp = idxbuf + (size_t)q * KNN;
  int cnt = 0, first = 0;
  for (int c = 0; c < N / 64 && cnt < KNN; ++c) {
    int pi = c * 64 + lane;
    const float* pp = pts + (size_t)pi * 3;
    float dx = __fsub_rn(ax, pp[0]);
    float dy = __fsub_rn(ay, pp[1]);
    float dz = __fsub_rn(az, pp[2]);
    float d2 = __fadd_rn(__fadd_rn(__fmul_rn(dx, dx), __fmul_rn(dy, dy)), __fmul_rn(dz, dz));
    bool hit = d2 < R2;
    unsigned long long mask = __ballot(hit);
    if (cnt == 0 && mask) first = c * 64 + (int)__builtin_ctzll(mask);
    int prefix = (int)__popcll(mask & ((1ull << lane) - 1ull));
    int slot = cnt + prefix;
    if (hit && slot < KNN) outp[slot] = pi;
    cnt += (int)__popcll(mask);
  }
  int cntK = cnt < KNN ? cnt : KNN;
  int fill = (cnt == 0) ? 0 : first;
  if (lane < KNN && lane >= cntK) outp[lane] = fill;
}

// ---------------- fused gather + dfeat + split-bf16 MFMA layer2 -------------
// wave = anchor; lane&15 = neighbor-within-ntile, lane>>4 = channel group.
// O(128x32) = W1 @ H, H = RFF[n] + relu(Wd@d4), via 3-term hi/lo bf16 MFMA.
__global__ __launch_bounds__(256) void mlp_kernel(const float* __restrict__ xyz,
                                                  const float* __restrict__ RFF,
                                                  const unsigned short* __restrict__ w1hi,
                                                  const unsigned short* __restrict__ w1lo,
                                                  const float* __restrict__ Wd,
                                                  const float* __restrict__ anchors,
                                                  const int* __restrict__ idxbuf,
                                                  float* __restrict__ out_feats) {
  __shared__ unsigned short Ah[8192];
  __shared__ unsigned short Al[8192];
  __shared__ float wd_l[256];
  __shared__ float fstage[4][128];
  int tid = threadIdx.x;
  {
    uint4* dh = (uint4*)Ah;
    const uint4* sh = (const uint4*)w1hi;
    uint4* dl = (uint4*)Al;
    const uint4* sl = (const uint4*)w1lo;
    for (int i = tid; i < 1024; i += 256) { dh[i] = sh[i]; dl[i] = sl[i]; }
    wd_l[tid] = Wd[tid];
  }
  __syncthreads();
  int w = tid >> 6, lane = tid & 63;
  int nloc = lane & 15, grp = lane >> 4;
  int bt = blockIdx.x >> 8;
  int m0 = (blockIdx.x & 255) * 4;
  int m = m0 + w;
  int b = bt >> 3, t = bt & 7;
  const float* anc = anchors + ((size_t)(bt * M + m)) * 3;
  float ax = anc[0], ay = anc[1], az = anc[2];
  f32x4 acc[8];
#pragma unroll
  for (int mt = 0; mt < 8; ++mt) acc[mt] = (f32x4){0.f, 0.f, 0.f, 0.f};
  for (int di = 0; di < 3; ++di) {
    int srct = t + di - 1;
    srct = srct < 0 ? 0 : (srct > 7 ? 7 : srct);
    const float* rf = RFF + ((size_t)(b * T + srct)) * N * 64;
    const float* pts = xyz + ((size_t)(b * T + srct)) * N * 3;
    const int* ip = idxbuf + ((size_t)((bt * 3 + di) * M + m)) * KNN;
    int n0 = ip[nloc];
    int n1 = ip[16 + nloc];
    float4 g[2][2][2];  // [nt][kt][half]
#pragma unroll
    for (int kt = 0; kt < 2; ++kt) {
      const float* r0 = rf + (size_t)n0 * 64 + kt * 32 + grp * 8;
      const float* r1 = rf + (size_t)n1 * 64 + kt * 32 + grp * 8;
      g[0][kt][0] = *(const float4*)&r0[0];
      g[0][kt][1] = *(const float4*)&r0[4];
      g[1][kt][0] = *(const float4*)&r1[0];
      g[1][kt][1] = *(const float4*)&r1[4];
    }
    float d4[2][4];
    d4[0][0] = pts[n0 * 3 + 0] - ax;
    d4[0][1] = pts[n0 * 3 + 1] - ay;
    d4[0][2] = pts[n0 * 3 + 2] - az;
    d4[1][0] = pts[n1 * 3 + 0] - ax;
    d4[1][1] = pts[n1 * 3 + 1] - ay;
    d4[1][2] = pts[n1 * 3 + 2] - az;
    d4[0][3] = d4[1][3] = (float)(di - 1);
    short8 Bh[2][2], Bl[2][2];  // [kt][nt]
#pragma unroll
    for (int kt = 0; kt < 2; ++kt)
#pragma unroll
      for (int nt = 0; nt < 2; ++nt) {
        short8 bh, bl;
#pragma unroll
        for (int j = 0; j < 8; ++j) {
          int ch = kt * 32 + grp * 8 + j;
          float4 wr = *(const float4*)&wd_l[ch * 4];
          float dd = fmaf(d4[nt][0], wr.x,
                     fmaf(d4[nt][1], wr.y, fmaf(d4[nt][2], wr.z, d4[nt][3] * wr.w)));
          const float* gp = (const float*)&g[nt][kt][j >> 2];
          float h = gp[j & 3] + fmaxf(dd, 0.f);
          unsigned short hi = f2bf(h);
          bh[j] = (short)hi;
          bl[j] = (short)f2bf(h - bf2f(hi));
        }
        Bh[kt][nt] = bh;
        Bl[kt][nt] = bl;
      }
    f32x4 c[8][2];
#pragma unroll
    for (int mt = 0; mt < 8; ++mt) {
      c[mt][0] = (f32x4){0.f, 0.f, 0.f, 0.f};
      c[mt][1] = (f32x4){0.f, 0.f, 0.f, 0.f};
    }
#pragma unroll
    for (int kt = 0; kt < 2; ++kt) {
#pragma unroll
      for (int mt = 0; mt < 8; ++mt) {
        int fo = ((kt * 8 + mt) * 64 + lane) * 8;
        short8 ahf = *(const short8*)&Ah[fo];
        short8 alf = *(const short8*)&Al[fo];
#pragma unroll
        for (int nt = 0; nt < 2; ++nt) {
          c[mt][nt] = __builtin_amdgcn_mfma_f32_16x16x32_bf16(ahf, Bh[kt][nt], c[mt][nt], 0, 0, 0);
          c[mt][nt] = __builtin_amdgcn_mfma_f32_16x16x32_bf16(ahf, Bl[kt][nt], c[mt][nt], 0, 0, 0);
          c[mt][nt] = __builtin_amdgcn_mfma_f32_16x16x32_bf16(alf, Bh[kt][nt], c[mt][nt], 0, 0, 0);
        }
      }
    }
    // relu(max over k): max over ntiles in regs, then 16-lane DPP reduce
#pragma unroll
    for (int mt = 0; mt < 8; ++mt)
#pragma unroll
      for (int r = 0; r < 4; ++r) {
        float o = fmaxf(c[mt][0][r], c[mt][1][r]);
        o = fmaxf(o, dppf<0xB1>(o));
        o = fmaxf(o, dppf<0x4E>(o));
        o = fmaxf(o, dppf<0x141>(o));
        o = fmaxf(o, dppf<0x140>(o));
        acc[mt][r] += fmaxf(o, 0.f);
      }
  }
  if (nloc == 0) {
#pragma unroll
    for (int mt = 0; mt < 8; ++mt)
#pragma unroll
      for (int r = 0; r < 4; ++r)
        fstage[w][mt * 16 + grp * 4 + r] = acc[mt][r];
  }
  __syncthreads();
  if (tid < 128) {
    float4 v = make_float4(fstage[0][tid], fstage[1][tid], fstage[2][tid], fstage[3][tid]);
    *(float4*)&out_feats[((size_t)(bt * C1 + tid)) * M + m0] = v;
  }
}

extern "C" void kernel_launch(void* const* d_in, const int* in_sizes, int n_in,
                              void* d_out, int out_size, void* d_ws, size_t ws_size,
                              hipStream_t stream) {
  const float* xyzs = (const float*)d_in[0];
  const float* feats = (const float*)d_in[1];
  const float* Wd = (const float*)d_in[2];
  const float* Wf = (const float*)d_in[3];
  const float* W1 = (const float*)d_in[4];
  float* out_xyz = (float*)d_out;                            // (B,8,M,3)
  float* out_feats = (float*)d_out + (size_t)B * T * M * 3;  // (B,8,C1,M)
  char* ws = (char*)d_ws;
  float* RFF = (float*)ws;                                          // 33.55 MB
  int* idxbuf = (int*)(ws + (size_t)B * T * N * 64 * 4);            // 12.58 MB
  char* tail = ws + (size_t)B * T * N * 64 * 4 + (size_t)B * T * 3 * M * KNN * 4;
  float* WfT = (float*)tail;                                        // 16 KB
  unsigned short* w1hi = (unsigned short*)(tail + 16384);           // 16 KB
  unsigned short* w1lo = (unsigned short*)(tail + 32768);           // 16 KB
  prep_wft<<<16, 256, 0, stream>>>(Wf, WfT);
  prep_w1frag<<<32, 256, 0, stream>>>(W1, w1hi, w1lo);
  rff_kernel<<<dim3(N / 64, B * T), 256, 0, stream>>>(feats, WfT, RFF);
  fps_kernel<<<B * T, 256, 0, stream>>>(xyzs, out_xyz);
  ballq_kernel<<<(B * T * 3 * M) / 4, 256, 0, stream>>>(xyzs, out_xyz, idxbuf);
  mlp_kernel<<<(B * T * M) / 4, 256, 0, stream>>>(xyzs, RFF, w1hi, w1lo, Wd, out_xyz,
                                                  idxbuf, out_feats);
}

// Round 5
// 1362.406 us; speedup vs baseline: 2.4872x; 1.2300x over previous
//
#include <hip/hip_runtime.h>

constexpr int B = 4, T = 8, N = 4096, C0 = 64, C1 = 128;
constexpr int M = 1024, KNN = 32;

typedef __attribute__((ext_vector_type(8))) short short8;
typedef __attribute__((ext_vector_type(4))) float f32x4;

__device__ __forceinline__ unsigned short f2bf(float x) {
  unsigned u = __float_as_uint(x);
  u = u + 0x7FFFu + ((u >> 16) & 1u);
  return (unsigned short)(u >> 16);
}
__device__ __forceinline__ float bf2f(unsigned short h) {
  return __uint_as_float((unsigned)h << 16);
}

template <int CTRL>
__device__ __forceinline__ float dppf(float x) {
  return __int_as_float(__builtin_amdgcn_update_dpp(0, __float_as_int(x), CTRL, 0xF, 0xF, true));
}
template <int CTRL>
__device__ __forceinline__ int dppi(int x) {
  return __builtin_amdgcn_update_dpp(0, x, CTRL, 0xF, 0xF, true);
}
template <int CTRL>
__device__ __forceinline__ unsigned long long dppu64(unsigned long long x) {
  unsigned lo = (unsigned)dppi<CTRL>((int)(unsigned)x);
  unsigned hi = (unsigned)dppi<CTRL>((int)(unsigned)(x >> 32));
  return ((unsigned long long)hi << 32) | lo;
}
__device__ __forceinline__ void kmerge(unsigned long long& a, unsigned long long b) {
  if (b > a) a = b;
}

// ---------------- prep: WfT[c][o] = Wf[o][c] --------------------------------
__global__ __launch_bounds__(256) void prep_wft(const float* __restrict__ Wf,
                                                float* __restrict__ WfT) {
  int t = blockIdx.x * 256 + threadIdx.x;
  if (t < 64 * 64) WfT[t] = Wf[(t & 63) * 64 + (t >> 6)];
}

// ---------------- prep: W1 -> MFMA A-fragment-ordered bf16 hi/lo ------------
__global__ __launch_bounds__(256) void prep_w1frag(const float* __restrict__ W1,
                                                   unsigned short* __restrict__ w1hi,
                                                   unsigned short* __restrict__ w1lo) {
  int t = blockIdx.x * 256 + threadIdx.x;
  if (t >= 8192) return;
  int j = t & 7, lane = (t >> 3) & 63, mt = (t >> 9) & 7, kt = t >> 12;
  int row = mt * 16 + (lane & 15);
  int k = kt * 32 + (lane >> 4) * 8 + j;
  float v = W1[row * 64 + k];
  unsigned short hi = f2bf(v);
  w1hi[t] = hi;
  w1lo[t] = f2bf(v - bf2f(hi));
}

// ---------------- RFF[n] = relu(Wf @ f_n), fused with transpose -------------
__global__ __launch_bounds__(256) void rff_kernel(const float* __restrict__ f,
                                                  const float* __restrict__ WfT,
                                                  float* __restrict__ RFF) {
  __shared__ float tile[64][65];
  int bt = blockIdx.y;
  int n0 = blockIdx.x * 64;
  const float* src = f + (size_t)bt * C0 * N;
  int tx = threadIdx.x & 63, ty = threadIdx.x >> 6;
  for (int r = ty; r < 64; r += 4)
    tile[r][tx] = src[(size_t)r * N + n0 + tx];
  __syncthreads();
  float acc[16];
#pragma unroll
  for (int oo = 0; oo < 16; ++oo) acc[oo] = 0.f;
  int obase = ty * 16;
#pragma unroll 4
  for (int c = 0; c < 64; ++c) {
    float fv = tile[c][tx];
    const float* wr = WfT + c * 64 + obase;
#pragma unroll
    for (int oo = 0; oo < 16; ++oo) acc[oo] = fmaf(fv, wr[oo], acc[oo]);
  }
  __syncthreads();
#pragma unroll
  for (int oo = 0; oo < 16; ++oo) tile[obase + oo][tx] = fmaxf(acc[oo], 0.f);
  __syncthreads();
  float* dst = RFF + ((size_t)bt * N + n0) * 64;
  for (int r = ty; r < 64; r += 4)
    dst[(size_t)r * 64 + tx] = tile[tx][r];
}

// ---------------- furthest point sampling v3 --------------------------------
// 256 thr / 16 pts per lane in regs. u64 (dist_bits, ~idx) keys; depth-4 local
// tree merge; 4 proven DPP xor-hops reduce each row-of-16; 16 LDS slots + one
// barrier; every thread merges all 16 (no shfl, no 2nd barrier).
__global__ __launch_bounds__(256) void fps_kernel(const float* __restrict__ xyz,
                                                  float* __restrict__ out_xyz) {
  __shared__ float4 P4[N];  // 64 KB
  __shared__ unsigned long long wslot[2][16];
  int bt = blockIdx.x;
  const float* p = xyz + (size_t)bt * N * 3;
  int tid = threadIdx.x;
  int lane = tid & 63, w = tid >> 6;
  for (int i = tid; i < N; i += 256)
    P4[i] = make_float4(p[i * 3 + 0], p[i * 3 + 1], p[i * 3 + 2], 0.f);
  __syncthreads();
  float X[16], Y[16], Z[16], D[16];
  unsigned inv[16];
#pragma unroll
  for (int j = 0; j < 16; ++j) {
    float4 v = P4[tid * 16 + j];
    X[j] = v.x; Y[j] = v.y; Z[j] = v.z;
    D[j] = 1e10f;
    inv[j] = ~(unsigned)(tid * 16 + j);
  }
  if (tid == 0) {
    float4 v = P4[0];
    out_xyz[(size_t)bt * M * 3 + 0] = v.x;
    out_xyz[(size_t)bt * M * 3 + 1] = v.y;
    out_xyz[(size_t)bt * M * 3 + 2] = v.z;
  }
  int lidx = 0;
  for (int s = 1; s < M; ++s) {
    float4 lp = P4[lidx];  // broadcast ds_read_b128
    unsigned long long k[16];
#pragma unroll
    for (int j = 0; j < 16; ++j) {
      float dx = __fsub_rn(X[j], lp.x);
      float dy = __fsub_rn(Y[j], lp.y);
      float dz = __fsub_rn(Z[j], lp.z);
      float d = __fadd_rn(__fadd_rn(__fmul_rn(dx, dx), __fmul_rn(dy, dy)), __fmul_rn(dz, dz));
      float nd = fminf(D[j], d);
      D[j] = nd;
      k[j] = ((unsigned long long)__float_as_uint(nd) << 32) | inv[j];
    }
    // depth-4 tree merge (dist asc, then smaller idx via larger ~idx)
#pragma unroll
    for (int st = 8; st >= 1; st >>= 1)
#pragma unroll
      for (int j = 0; j < st; ++j) kmerge(k[j], k[j + st]);
    unsigned long long best = k[0];
    // in-row (16-lane) reduce: proven DPP xor hops
    kmerge(best, dppu64<0xB1>(best));
    kmerge(best, dppu64<0x4E>(best));
    kmerge(best, dppu64<0x141>(best));
    kmerge(best, dppu64<0x140>(best));
    int buf = s & 1;
    if ((lane & 15) == 0) wslot[buf][w * 4 + (lane >> 4)] = best;
    __syncthreads();
    unsigned long long g = wslot[buf][0];
#pragma unroll
    for (int q = 1; q < 16; ++q) kmerge(g, wslot[buf][q]);
    lidx = (int)(~(unsigned)g);
    if (tid == 0) {
      float4 v = P4[lidx];
      out_xyz[((size_t)(bt * M + s)) * 3 + 0] = v.x;
      out_xyz[((size_t)(bt * M + s)) * 3 + 1] = v.y;
      out_xyz[((size_t)(bt * M + s)) * 3 + 2] = v.z;
    }
  }
}

// ---------------- ball query: one wave per (b,t,di,m) -----------------------
__global__ __launch_bounds__(256) void ballq_kernel(const float* __restrict__ xyz,
                                                    const float* __restrict__ anchors,
                                                    int* __restrict__ idxbuf) {
  const float R2 = 0.04f;
  int w = threadIdx.x >> 6, lane = threadIdx.x & 63;
  int q = blockIdx.x * 4 + w;
  int m = q & (M - 1);
  int di = (q >> 10) % 3;
  int bt = q / (M * 3);
  int b = bt >> 3, t = bt & 7;
  int srct = t + di - 1;
  srct = srct < 0 ? 0 : (srct > 7 ? 7 : srct);
  const float* anc = anchors + ((size_t)(bt * M + m)) * 3;
  float ax = anc[0], ay = anc[1], az = anc[2];
  const float* pts = xyz + ((size_t)(b * T + srct)) * N * 3;
  int* outp = idxbuf + (size_t)q * KNN;
  int cnt = 0, first = 0;
  for (int c = 0; c < N / 64 && cnt < KNN; ++c) {
    int pi = c * 64 + lane;
    const float* pp = pts + (size_t)pi * 3;
    float dx = __fsub_rn(ax, pp[0]);
    float dy = __fsub_rn(ay, pp[1]);
    float dz = __fsub_rn(az, pp[2]);
    float d2 = __fadd_rn(__fadd_rn(__fmul_rn(dx, dx), __fmul_rn(dy, dy)), __fmul_rn(dz, dz));
    bool hit = d2 < R2;
    unsigned long long mask = __ballot(hit);
    if (cnt == 0 && mask) first = c * 64 + (int)__builtin_ctzll(mask);
    int prefix = (int)__popcll(mask & ((1ull << lane) - 1ull));
    int slot = cnt + prefix;
    if (hit && slot < KNN) outp[slot] = pi;
    cnt += (int)__popcll(mask);
  }
  int cntK = cnt < KNN ? cnt : KNN;
  int fill = (cnt == 0) ? 0 : first;
  if (lane < KNN && lane >= cntK) outp[lane] = fill;
}

// ---------------- fused gather + dfeat + split-bf16 MFMA layer2 -------------
// wave = anchor; di fully unrolled with register double-buffered prefetch of
// (indices, RFF rows, pts) for di+1 issued before computing di. Opaque-zero
// LDS bases stop cross-di CSE of A-fragment/Wd reads (VGPR blowup).
__global__ __launch_bounds__(256) void mlp_kernel(const float* __restrict__ xyz,
                                                  const float* __restrict__ RFF,
                                                  const unsigned short* __restrict__ w1hi,
                                                  const unsigned short* __restrict__ w1lo,
                                                  const float* __restrict__ Wd,
                                                  const float* __restrict__ anchors,
                                                  const int* __restrict__ idxbuf,
                                                  float* __restrict__ out_feats) {
  __shared__ unsigned short Ah[8192];
  __shared__ unsigned short Al[8192];
  __shared__ float wd_l[256];
  __shared__ float fstage[4][128];
  int tid = threadIdx.x;
  {
    uint4* dh = (uint4*)Ah;
    const uint4* sh = (const uint4*)w1hi;
    uint4* dl = (uint4*)Al;
    const uint4* sl = (const uint4*)w1lo;
    for (int i = tid; i < 1024; i += 256) { dh[i] = sh[i]; dl[i] = sl[i]; }
    wd_l[tid] = Wd[tid];
  }
  __syncthreads();
  int w = tid >> 6, lane = tid & 63;
  int nloc = lane & 15, grp = lane >> 4;
  int bt = blockIdx.x >> 8;
  int m0 = (blockIdx.x & 255) * 4;
  int m = m0 + w;
  int b = bt >> 3, t = bt & 7;
  int aoff = __builtin_amdgcn_readfirstlane(bt * M + m);
  float ax = anchors[(size_t)aoff * 3 + 0];
  float ay = anchors[(size_t)aoff * 3 + 1];
  float az = anchors[(size_t)aoff * 3 + 2];
  f32x4 acc[8];
#pragma unroll
  for (int mt = 0; mt < 8; ++mt) acc[mt] = (f32x4){0.f, 0.f, 0.f, 0.f};

  float4 pg[2][2][2][2];  // [buf][nt][kt][half]
  float ppx[2][2], ppy[2][2], ppz[2][2];

#define MLOADP(BUF, DI)                                                        \
  {                                                                            \
    int srct = t + (DI)-1;                                                     \
    srct = srct < 0 ? 0 : (srct > 7 ? 7 : srct);                               \
    const float* rf = RFF + ((size_t)(b * T + srct)) * N * 64;                 \
    const float* pts = xyz + ((size_t)(b * T + srct)) * N * 3;                 \
    const int* ip = idxbuf + ((size_t)((bt * 3 + (DI)) * M + m)) * KNN;        \
    int n0 = ip[nloc], n1 = ip[16 + nloc];                                     \
    _Pragma("unroll") for (int kt = 0; kt < 2; ++kt) {                         \
      const float* r0 = rf + (size_t)n0 * 64 + kt * 32 + grp * 8;              \
      const float* r1 = rf + (size_t)n1 * 64 + kt * 32 + grp * 8;              \
      pg[BUF][0][kt][0] = *(const float4*)&r0[0];                              \
      pg[BUF][0][kt][1] = *(const float4*)&r0[4];                              \
      pg[BUF][1][kt][0] = *(const float4*)&r1[0];                              \
      pg[BUF][1][kt][1] = *(const float4*)&r1[4];                              \
    }                                                                          \
    ppx[BUF][0] = pts[n0 * 3 + 0];                                             \
    ppy[BUF][0] = pts[n0 * 3 + 1];                                             \
    ppz[BUF][0] = pts[n0 * 3 + 2];                                             \
    ppx[BUF][1] = pts[n1 * 3 + 0];                                             \
    ppy[BUF][1] = pts[n1 * 3 + 1];                                             \
    ppz[BUF][1] = pts[n1 * 3 + 2];                                             \
  }

#define MCOMPUTE(BUF, DI)                                                      \
  {                                                                            \
    int zro = 0;                                                               \
    asm volatile("" : "+v"(zro));                                              \
    const unsigned short* AhO = Ah + zro;                                      \
    const unsigned short* AlO = Al + zro;                                      \
    const float* wdO = (const float*)wd_l + zro;                               \
    float tvv = (float)((DI)-1);                                               \
    short8 Bh[2][2], Bl[2][2];                                                 \
    _Pragma("unroll") for (int kt = 0; kt < 2; ++kt)                           \
        _Pragma("unroll") for (int nt = 0; nt < 2; ++nt) {                     \
      float dx = ppx[BUF][nt] - ax;                                            \
      float dy = ppy[BUF][nt] - ay;                                            \
      float dz = ppz[BUF][nt] - az;                                            \
      short8 bh, bl;                                                           \
      _Pragma("unroll") for (int j = 0; j < 8; ++j) {                          \
        int ch = kt * 32 + grp * 8 + j;                                        \
        float4 wr = *(const float4*)&wdO[ch * 4];                              \
        float dd = fmaf(dx, wr.x, fmaf(dy, wr.y, fmaf(dz, wr.z, tvv * wr.w))); \
        const float* gp = (const float*)&pg[BUF][nt][kt][j >> 2];              \
        float h = gp[j & 3] + fmaxf(dd, 0.f);                                  \
        unsigned short hi_ = f2bf(h);                                          \
        bh[j] = (short)hi_;                                                    \
        bl[j] = (short)f2bf(h - bf2f(hi_));                                    \
      }                                                                        \
      Bh[kt][nt] = bh;                                                         \
      Bl[kt][nt] = bl;                                                         \
    }                                                                          \
    f32x4 c[8][2];                                                             \
    _Pragma("unroll") for (int mt = 0; mt < 8; ++mt) {                         \
      c[mt][0] = (f32x4){0.f, 0.f, 0.f, 0.f};                                  \
      c[mt][1] = (f32x4){0.f, 0.f, 0.f, 0.f};                                  \
    }                                                                          \
    _Pragma("unroll") for (int kt = 0; kt < 2; ++kt) {                         \
      _Pragma("unroll") for (int mt = 0; mt < 8; ++mt) {                       \
        int fo = ((kt * 8 + mt) * 64 + lane) * 8;                              \
        short8 ahf = *(const short8*)&AhO[fo];                                 \
        short8 alf = *(const short8*)&AlO[fo];                                 \
        _Pragma("unroll") for (int nt = 0; nt < 2; ++nt) {                     \
          c[mt][nt] =                                                          \
              __builtin_amdgcn_mfma_f32_16x16x32_bf16(ahf, Bh[kt][nt], c[mt][nt], 0, 0, 0); \
          c[mt][nt] =                                                          \
              __builtin_amdgcn_mfma_f32_16x16x32_bf16(ahf, Bl[kt][nt], c[mt][nt], 0, 0, 0); \
          c[mt][nt] =                                                          \
              __builtin_amdgcn_mfma_f32_16x16x32_bf16(alf, Bh[kt][nt], c[mt][nt], 0, 0, 0); \
        }                                                                      \
      }                                                                        \
    }                                                                          \
    _Pragma("unroll") for (int mt = 0; mt < 8; ++mt)                           \
        _Pragma("unroll") for (int r = 0; r < 4; ++r) {                        \
      float o = fmaxf(c[mt][0][r], c[mt][1][r]);                               \
      o = fmaxf(o, dppf<0xB1>(o));                                             \
      o = fmaxf(o, dppf<0x4E>(o));                                             \
      o = fmaxf(o, dppf<0x141>(o));                                            \
      o = fmaxf(o, dppf<0x140>(o));                                            \
      acc[mt][r] += fmaxf(o, 0.f);                                             \
    }                                                                          \
  }

  MLOADP(0, 0)
  MLOADP(1, 1)
  MCOMPUTE(0, 0)
  MLOADP(0, 2)
  MCOMPUTE(1, 1)
  MCOMPUTE(0, 2)
#undef MLOADP
#undef MCOMPUTE

  if (nloc == 0) {
#pragma unroll
    for (int mt = 0; mt < 8; ++mt)
#pragma unroll
      for (int r = 0; r < 4; ++r)
        fstage[w][mt * 16 + grp * 4 + r] = acc[mt][r];
  }
  __syncthreads();
  if (tid < 128) {
    float4 v = make_float4(fstage[0][tid], fstage[1][tid], fstage[2][tid], fstage[3][tid]);
    *(float4*)&out_feats[((size_t)(bt * C1 + tid)) * M + m0] = v;
  }
}

extern "C" void kernel_launch(void* const* d_in, const int* in_sizes, int n_in,
                              void* d_out, int out_size, void* d_ws, size_t ws_size,
                              hipStream_t stream) {
  const float* xyzs = (const float*)d_in[0];
  const float* feats = (const float*)d_in[1];
  const float* Wd = (const float*)d_in[2];
  const float* Wf = (const float*)d_in[3];
  const float* W1 = (const float*)d_in[4];
  float* out_xyz = (float*)d_out;                            // (B,8,M,3)
  float* out_feats = (float*)d_out + (size_t)B * T * M * 3;  // (B,8,C1,M)
  char* ws = (char*)d_ws;
  float* RFF = (float*)ws;                                          // 33.55 MB
  int* idxbuf = (int*)(ws + (size_t)B * T * N * 64 * 4);            // 12.58 MB
  char* tail = ws + (size_t)B * T * N * 64 * 4 + (size_t)B * T * 3 * M * KNN * 4;
  float* WfT = (float*)tail;                                        // 16 KB
  unsigned short* w1hi = (unsigned short*)(tail + 16384);           // 16 KB
  unsigned short* w1lo = (unsigned short*)(tail + 32768);           // 16 KB
  prep_wft<<<16, 256, 0, stream>>>(Wf, WfT);
  prep_w1frag<<<32, 256, 0, stream>>>(W1, w1hi, w1lo);
  rff_kernel<<<dim3(N / 64, B * T), 256, 0, stream>>>(feats, WfT, RFF);
  fps_kernel<<<B * T, 256, 0, stream>>>(xyzs, out_xyz);
  ballq_kernel<<<(B * T * 3 * M) / 4, 256, 0, stream>>>(xyzs, out_xyz, idxbuf);
  mlp_kernel<<<(B * T * M) / 4, 256, 0, stream>>>(xyzs, RFF, w1hi, w1lo, Wd, out_xyz,
                                                  idxbuf, out_feats);
}

// Round 6
// 1334.812 us; speedup vs baseline: 2.5386x; 1.0207x over previous
//
#include <hip/hip_runtime.h>

constexpr int B = 4, T = 8, N = 4096, C0 = 64, C1 = 128;
constexpr int M = 1024, KNN = 32;

typedef __attribute__((ext_vector_type(8))) short short8;
typedef __attribute__((ext_vector_type(4))) float f32x4;

__device__ __forceinline__ unsigned short f2bf(float x) {
  unsigned u = __float_as_uint(x);
  u = u + 0x7FFFu + ((u >> 16) & 1u);
  return (unsigned short)(u >> 16);
}
__device__ __forceinline__ float bf2f(unsigned short h) {
  return __uint_as_float((unsigned)h << 16);
}

template <int CTRL>
__device__ __forceinline__ float dppf(float x) {
  return __int_as_float(__builtin_amdgcn_update_dpp(0, __float_as_int(x), CTRL, 0xF, 0xF, true));
}
template <int CTRL>
__device__ __forceinline__ int dppi(int x) {
  return __builtin_amdgcn_update_dpp(0, x, CTRL, 0xF, 0xF, true);
}
template <int CTRL>
__device__ __forceinline__ unsigned long long dppu64(unsigned long long x) {
  unsigned lo = (unsigned)dppi<CTRL>((int)(unsigned)x);
  unsigned hi = (unsigned)dppi<CTRL>((int)(unsigned)(x >> 32));
  return ((unsigned long long)hi << 32) | lo;
}
__device__ __forceinline__ void kmerge(unsigned long long& a, unsigned long long b) {
  if (b > a) a = b;
}
__device__ __forceinline__ unsigned long long kmax(unsigned long long a, unsigned long long b) {
  return b > a ? b : a;
}

// ---------------- prep: WfT[c][o] = Wf[o][c] --------------------------------
__global__ __launch_bounds__(256) void prep_wft(const float* __restrict__ Wf,
                                                float* __restrict__ WfT) {
  int t = blockIdx.x * 256 + threadIdx.x;
  if (t < 64 * 64) WfT[t] = Wf[(t & 63) * 64 + (t >> 6)];
}

// ---------------- prep: W1 -> MFMA A-fragment-ordered bf16 hi/lo ------------
__global__ __launch_bounds__(256) void prep_w1frag(const float* __restrict__ W1,
                                                   unsigned short* __restrict__ w1hi,
                                                   unsigned short* __restrict__ w1lo) {
  int t = blockIdx.x * 256 + threadIdx.x;
  if (t >= 8192) return;
  int j = t & 7, lane = (t >> 3) & 63, mt = (t >> 9) & 7, kt = t >> 12;
  int row = mt * 16 + (lane & 15);
  int k = kt * 32 + (lane >> 4) * 8 + j;
  float v = W1[row * 64 + k];
  unsigned short hi = f2bf(v);
  w1hi[t] = hi;
  w1lo[t] = f2bf(v - bf2f(hi));
}

// ---------------- RFF[n] = relu(Wf @ f_n), fused with transpose -------------
__global__ __launch_bounds__(256) void rff_kernel(const float* __restrict__ f,
                                                  const float* __restrict__ WfT,
                                                  float* __restrict__ RFF) {
  __shared__ float tile[64][65];
  int bt = blockIdx.y;
  int n0 = blockIdx.x * 64;
  const float* src = f + (size_t)bt * C0 * N;
  int tx = threadIdx.x & 63, ty = threadIdx.x >> 6;
  for (int r = ty; r < 64; r += 4)
    tile[r][tx] = src[(size_t)r * N + n0 + tx];
  __syncthreads();
  float acc[16];
#pragma unroll
  for (int oo = 0; oo < 16; ++oo) acc[oo] = 0.f;
  int obase = ty * 16;
#pragma unroll 4
  for (int c = 0; c < 64; ++c) {
    float fv = tile[c][tx];
    const float* wr = WfT + c * 64 + obase;
#pragma unroll
    for (int oo = 0; oo < 16; ++oo) acc[oo] = fmaf(fv, wr[oo], acc[oo]);
  }
  __syncthreads();
#pragma unroll
  for (int oo = 0; oo < 16; ++oo) tile[obase + oo][tx] = fmaxf(acc[oo], 0.f);
  __syncthreads();
  float* dst = RFF + ((size_t)bt * N + n0) * 64;
  for (int r = ty; r < 64; r += 4)
    dst[(size_t)r * 64 + tx] = tile[tx][r];
}

// ---------------- furthest point sampling v4 --------------------------------
// 256 thr / 16 pts per lane (interleaved: lane j holds j*256+tid -> conflict-
// free init). u64 (dist_bits, ~idx) keys; depth-4 local tree; 4 DPP xor hops;
// 16 LDS slots + one barrier; picks recorded in LDS, ALL global stores after
// the loop (keeps vmcnt drain out of the serial chain).
__global__ __launch_bounds__(256) void fps_kernel(const float* __restrict__ xyz,
                                                  float* __restrict__ out_xyz) {
  __shared__ float4 P4[N];  // 64 KB
  __shared__ unsigned long long wslot[2][16];
  __shared__ int pick_l[M];  // 4 KB
  int bt = blockIdx.x;
  const float* p = xyz + (size_t)bt * N * 3;
  int tid = threadIdx.x;
  int lane = tid & 63, w = tid >> 6;
  for (int i = tid; i < N; i += 256)
    P4[i] = make_float4(p[i * 3 + 0], p[i * 3 + 1], p[i * 3 + 2], 0.f);
  if (tid == 0) pick_l[0] = 0;
  __syncthreads();
  float X[16], Y[16], Z[16], D[16];
  unsigned inv[16];
#pragma unroll
  for (int j = 0; j < 16; ++j) {
    float4 v = P4[j * 256 + tid];  // consecutive lanes -> consecutive banks
    X[j] = v.x; Y[j] = v.y; Z[j] = v.z;
    D[j] = 1e10f;
    inv[j] = ~(unsigned)(j * 256 + tid);
  }
  int lidx = 0;
  for (int s = 1; s < M; ++s) {
    float4 lp = P4[lidx];  // broadcast ds_read_b128
    unsigned long long k[16];
#pragma unroll
    for (int j = 0; j < 16; ++j) {
      float dx = __fsub_rn(X[j], lp.x);
      float dy = __fsub_rn(Y[j], lp.y);
      float dz = __fsub_rn(Z[j], lp.z);
      float d = __fadd_rn(__fadd_rn(__fmul_rn(dx, dx), __fmul_rn(dy, dy)), __fmul_rn(dz, dz));
      float nd = fminf(D[j], d);
      D[j] = nd;
      k[j] = ((unsigned long long)__float_as_uint(nd) << 32) | inv[j];
    }
    // depth-4 tree merge (dist desc, then smaller idx via larger ~idx)
#pragma unroll
    for (int st = 8; st >= 1; st >>= 1)
#pragma unroll
      for (int j = 0; j < st; ++j) kmerge(k[j], k[j + st]);
    unsigned long long best = k[0];
    kmerge(best, dppu64<0xB1>(best));
    kmerge(best, dppu64<0x4E>(best));
    kmerge(best, dppu64<0x141>(best));
    kmerge(best, dppu64<0x140>(best));
    int buf = s & 1;
    if ((lane & 15) == 0) wslot[buf][w * 4 + (lane >> 4)] = best;
    __syncthreads();
    // explicit tree over the 16 slots (broadcast reads)
    unsigned long long t0 = kmax(wslot[buf][0], wslot[buf][1]);
    unsigned long long t1 = kmax(wslot[buf][2], wslot[buf][3]);
    unsigned long long t2 = kmax(wslot[buf][4], wslot[buf][5]);
    unsigned long long t3 = kmax(wslot[buf][6], wslot[buf][7]);
    unsigned long long t4 = kmax(wslot[buf][8], wslot[buf][9]);
    unsigned long long t5 = kmax(wslot[buf][10], wslot[buf][11]);
    unsigned long long t6 = kmax(wslot[buf][12], wslot[buf][13]);
    unsigned long long t7 = kmax(wslot[buf][14], wslot[buf][15]);
    unsigned long long g = kmax(kmax(kmax(t0, t1), kmax(t2, t3)),
                                kmax(kmax(t4, t5), kmax(t6, t7)));
    lidx = (int)(~(unsigned)g);
    if (tid == 0) pick_l[s] = lidx;  // LDS only; no global store in loop
  }
  __syncthreads();
  float* outp = out_xyz + (size_t)bt * M * 3;
  for (int mm = tid; mm < M; mm += 256) {
    float4 v = P4[pick_l[mm]];
    outp[mm * 3 + 0] = v.x;
    outp[mm * 3 + 1] = v.y;
    outp[mm * 3 + 2] = v.z;
  }
}

// ---------------- ball query: one wave per (b,t,di,m) -----------------------
__global__ __launch_bounds__(256) void ballq_kernel(const float* __restrict__ xyz,
                                                    const float* __restrict__ anchors,
                                                    int* __restrict__ idxbuf) {
  const float R2 = 0.04f;
  int w = threadIdx.x >> 6, lane = threadIdx.x & 63;
  int q = blockIdx.x * 4 + w;
  int m = q & (M - 1);
  int di = (q >> 10) % 3;
  int bt = q / (M * 3);
  int b = bt >> 3, t = bt & 7;
  int srct = t + di - 1;
  srct = srct < 0 ? 0 : (srct > 7 ? 7 : srct);
  const float* anc = anchors + ((size_t)(bt * M + m)) * 3;
  float ax = anc[0], ay = anc[1], az = anc[2];
  const float* pts = xyz + ((size_t)(b * T + srct)) * N * 3;
  int* outp = idxbuf + (size_t)q * KNN;
  int cnt = 0, first = 0;
  for (int c = 0; c < N / 64 && cnt < KNN; ++c) {
    int pi = c * 64 + lane;
    const float* pp = pts + (size_t)pi * 3;
    float dx = __fsub_rn(ax, pp[0]);
    float dy = __fsub_rn(ay, pp[1]);
    float dz = __fsub_rn(az, pp[2]);
    float d2 = __fadd_rn(__fadd_rn(__fmul_rn(dx, dx), __fmul_rn(dy, dy)), __fmul_rn(dz, dz));
    bool hit = d2 < R2;
    unsigned long long mask = __ballot(hit);
    if (cnt == 0 && mask) first = c * 64 + (int)__builtin_ctzll(mask);
    int prefix = (int)__popcll(mask & ((1ull << lane) - 1ull));
    int slot = cnt + prefix;
    if (hit && slot < KNN) outp[slot] = pi;
    cnt += (int)__popcll(mask);
  }
  int cntK = cnt < KNN ? cnt : KNN;
  int fill = (cnt == 0) ? 0 : first;
  if (lane < KNN && lane >= cntK) outp[lane] = fill;
}

// ---------------- fused gather + dfeat + split-bf16 MFMA layer2 -------------
__global__ __launch_bounds__(256) void mlp_kernel(const float* __restrict__ xyz,
                                                  const float* __restrict__ RFF,
                                                  const unsigned short* __restrict__ w1hi,
                                                  const unsigned short* __restrict__ w1lo,
                                                  const float* __restrict__ Wd,
                                                  const float* __restrict__ anchors,
                                                  const int* __restrict__ idxbuf,
                                                  float* __restrict__ out_feats) {
  __shared__ unsigned short Ah[8192];
  __shared__ unsigned short Al[8192];
  __shared__ float wd_l[256];
  __shared__ float fstage[4][128];
  int tid = threadIdx.x;
  {
    uint4* dh = (uint4*)Ah;
    const uint4* sh = (const uint4*)w1hi;
    uint4* dl = (uint4*)Al;
    const uint4* sl = (const uint4*)w1lo;
    for (int i = tid; i < 1024; i += 256) { dh[i] = sh[i]; dl[i] = sl[i]; }
    wd_l[tid] = Wd[tid];
  }
  __syncthreads();
  int w = tid >> 6, lane = tid & 63;
  int nloc = lane & 15, grp = lane >> 4;
  int bt = blockIdx.x >> 8;
  int m0 = (blockIdx.x & 255) * 4;
  int m = m0 + w;
  int b = bt >> 3, t = bt & 7;
  int aoff = __builtin_amdgcn_readfirstlane(bt * M + m);
  float ax = anchors[(size_t)aoff * 3 + 0];
  float ay = anchors[(size_t)aoff * 3 + 1];
  float az = anchors[(size_t)aoff * 3 + 2];
  f32x4 acc[8];
#pragma unroll
  for (int mt = 0; mt < 8; ++mt) acc[mt] = (f32x4){0.f, 0.f, 0.f, 0.f};

  float4 pg[2][2][2][2];  // [buf][nt][kt][half]
  float ppx[2][2], ppy[2][2], ppz[2][2];

#define MLOADP(BUF, DI)                                                        \
  {                                                                            \
    int srct = t + (DI)-1;                                                     \
    srct = srct < 0 ? 0 : (srct > 7 ? 7 : srct);                               \
    const float* rf = RFF + ((size_t)(b * T + srct)) * N * 64;                 \
    const float* pts = xyz + ((size_t)(b * T + srct)) * N * 3;                 \
    const int* ip = idxbuf + ((size_t)((bt * 3 + (DI)) * M + m)) * KNN;        \
    int n0 = ip[nloc], n1 = ip[16 + nloc];                                     \
    _Pragma("unroll") for (int kt = 0; kt < 2; ++kt) {                         \
      const float* r0 = rf + (size_t)n0 * 64 + kt * 32 + grp * 8;              \
      const float* r1 = rf + (size_t)n1 * 64 + kt * 32 + grp * 8;              \
      pg[BUF][0][kt][0] = *(const float4*)&r0[0];                              \
      pg[BUF][0][kt][1] = *(const float4*)&r0[4];                              \
      pg[BUF][1][kt][0] = *(const float4*)&r1[0];                              \
      pg[BUF][1][kt][1] = *(const float4*)&r1[4];                              \
    }                                                                          \
    ppx[BUF][0] = pts[n0 * 3 + 0];                                             \
    ppy[BUF][0] = pts[n0 * 3 + 1];                                             \
    ppz[BUF][0] = pts[n0 * 3 + 2];                                             \
    ppx[BUF][1] = pts[n1 * 3 + 0];                                             \
    ppy[BUF][1] = pts[n1 * 3 + 1];                                             \
    ppz[BUF][1] = pts[n1 * 3 + 2];                                             \
  }

#define MCOMPUTE(BUF, DI)                                                      \
  {                                                                            \
    int zro = 0;                                                               \
    asm volatile("" : "+v"(zro));                                              \
    const unsigned short* AhO = Ah + zro;                                      \
    const unsigned short* AlO = Al + zro;                                      \
    const float* wdO = (const float*)wd_l + zro;                               \
    float tvv = (float)((DI)-1);                                               \
    short8 Bh[2][2], Bl[2][2];                                                 \
    _Pragma("unroll") for (int kt = 0; kt < 2; ++kt)                           \
        _Pragma("unroll") for (int nt = 0; nt < 2; ++nt) {                     \
      float dx = ppx[BUF][nt] - ax;                                            \
      float dy = ppy[BUF][nt] - ay;                                            \
      float dz = ppz[BUF][nt] - az;                                            \
      short8 bh, bl;                                                           \
      _Pragma("unroll") for (int j = 0; j < 8; ++j) {                          \
        int ch = kt * 32 + grp * 8 + j;                                        \
        float4 wr = *(const float4*)&wdO[ch * 4];                              \
        float dd = fmaf(dx, wr.x, fmaf(dy, wr.y, fmaf(dz, wr.z, tvv * wr.w))); \
        const float* gp = (const float*)&pg[BUF][nt][kt][j >> 2];              \
        float h = gp[j & 3] + fmaxf(dd, 0.f);                                  \
        unsigned short hi_ = f2bf(h);                                          \
        bh[j] = (short)hi_;                                                    \
        bl[j] = (short)f2bf(h - bf2f(hi_));                                    \
      }                                                                        \
      Bh[kt][nt] = bh;                                                         \
      Bl[kt][nt] = bl;                                                         \
    }                                                                          \
    f32x4 c[8][2];                                                             \
    _Pragma("unroll") for (int mt = 0; mt < 8; ++mt) {                         \
      c[mt][0] = (f32x4){0.f, 0.f, 0.f, 0.f};                                  \
      c[mt][1] = (f32x4){0.f, 0.f, 0.f, 0.f};                                  \
    }                                                                          \
    _Pragma("unroll") for (int kt = 0; kt < 2; ++kt) {                         \
      _Pragma("unroll") for (int mt = 0; mt < 8; ++mt) {                       \
        int fo = ((kt * 8 + mt) * 64 + lane) * 8;                              \
        short8 ahf = *(const short8*)&AhO[fo];                                 \
        short8 alf = *(const short8*)&AlO[fo];                                 \
        _Pragma("unroll") for (int nt = 0; nt < 2; ++nt) {                     \
          c[mt][nt] =                                                          \
              __builtin_amdgcn_mfma_f32_16x16x32_bf16(ahf, Bh[kt][nt], c[mt][nt], 0, 0, 0); \
          c[mt][nt] =                                                          \
              __builtin_amdgcn_mfma_f32_16x16x32_bf16(ahf, Bl[kt][nt], c[mt][nt], 0, 0, 0); \
          c[mt][nt] =                                                          \
              __builtin_amdgcn_mfma_f32_16x16x32_bf16(alf, Bh[kt][nt], c[mt][nt], 0, 0, 0); \
        }                                                                      \
      }                                                                        \
    }                                                                          \
    _Pragma("unroll") for (int mt = 0; mt < 8; ++mt)                           \
        _Pragma("unroll") for (int r = 0; r < 4; ++r) {                        \
      float o = fmaxf(c[mt][0][r], c[mt][1][r]);                               \
      o = fmaxf(o, dppf<0xB1>(o));                                             \
      o = fmaxf(o, dppf<0x4E>(o));                                             \
      o = fmaxf(o, dppf<0x141>(o));                                            \
      o = fmaxf(o, dppf<0x140>(o));                                            \
      acc[mt][r] += fmaxf(o, 0.f);                                             \
    }                                                                          \
  }

  MLOADP(0, 0)
  MLOADP(1, 1)
  MCOMPUTE(0, 0)
  MLOADP(0, 2)
  MCOMPUTE(1, 1)
  MCOMPUTE(0, 2)
#undef MLOADP
#undef MCOMPUTE

  if (nloc == 0) {
#pragma unroll
    for (int mt = 0; mt < 8; ++mt)
#pragma unroll
      for (int r = 0; r < 4; ++r)
        fstage[w][mt * 16 + grp * 4 + r] = acc[mt][r];
  }
  __syncthreads();
  if (tid < 128) {
    float4 v = make_float4(fstage[0][tid], fstage[1][tid], fstage[2][tid], fstage[3][tid]);
    *(float4*)&out_feats[((size_t)(bt * C1 + tid)) * M + m0] = v;
  }
}

extern "C" void kernel_launch(void* const* d_in, const int* in_sizes, int n_in,
                              void* d_out, int out_size, void* d_ws, size_t ws_size,
                              hipStream_t stream) {
  const float* xyzs = (const float*)d_in[0];
  const float* feats = (const float*)d_in[1];
  const float* Wd = (const float*)d_in[2];
  const float* Wf = (const float*)d_in[3];
  const float* W1 = (const float*)d_in[4];
  float* out_xyz = (float*)d_out;                            // (B,8,M,3)
  float* out_feats = (float*)d_out + (size_t)B * T * M * 3;  // (B,8,C1,M)
  char* ws = (char*)d_ws;
  float* RFF = (float*)ws;                                          // 33.55 MB
  int* idxbuf = (int*)(ws + (size_t)B * T * N * 64 * 4);            // 12.58 MB
  char* tail = ws + (size_t)B * T * N * 64 * 4 + (size_t)B * T * 3 * M * KNN * 4;
  float* WfT = (float*)tail;                                        // 16 KB
  unsigned short* w1hi = (unsigned short*)(tail + 16384);           // 16 KB
  unsigned short* w1lo = (unsigned short*)(tail + 32768);           // 16 KB
  prep_wft<<<16, 256, 0, stream>>>(Wf, WfT);
  prep_w1frag<<<32, 256, 0, stream>>>(W1, w1hi, w1lo);
  rff_kernel<<<dim3(N / 64, B * T), 256, 0, stream>>>(feats, WfT, RFF);
  fps_kernel<<<B * T, 256, 0, stream>>>(xyzs, out_xyz);
  ballq_kernel<<<(B * T * 3 * M) / 4, 256, 0, stream>>>(xyzs, out_xyz, idxbuf);
  mlp_kernel<<<(B * T * M) / 4, 256, 0, stream>>>(xyzs, RFF, w1hi, w1lo, Wd, out_xyz,
                                                  idxbuf, out_feats);
}

// Round 7
// 1281.681 us; speedup vs baseline: 2.6439x; 1.0415x over previous
//
#include <hip/hip_runtime.h>

constexpr int B = 4, T = 8, N = 4096, C0 = 64, C1 = 128;
constexpr int M = 1024, KNN = 32;

typedef __attribute__((ext_vector_type(8))) short short8;
typedef __attribute__((ext_vector_type(4))) float f32x4;

__device__ __forceinline__ unsigned short f2bf(float x) {
  unsigned u = __float_as_uint(x);
  u = u + 0x7FFFu + ((u >> 16) & 1u);
  return (unsigned short)(u >> 16);
}
__device__ __forceinline__ float bf2f(unsigned short h) {
  return __uint_as_float((unsigned)h << 16);
}

template <int CTRL>
__device__ __forceinline__ float dppf(float x) {
  return __int_as_float(__builtin_amdgcn_update_dpp(0, __float_as_int(x), CTRL, 0xF, 0xF, true));
}
template <int CTRL>
__device__ __forceinline__ int dppi(int x) {
  return __builtin_amdgcn_update_dpp(0, x, CTRL, 0xF, 0xF, true);
}
template <int CTRL>
__device__ __forceinline__ unsigned long long dppu64(unsigned long long x) {
  unsigned lo = (unsigned)dppi<CTRL>((int)(unsigned)x);
  unsigned hi = (unsigned)dppi<CTRL>((int)(unsigned)(x >> 32));
  return ((unsigned long long)hi << 32) | lo;
}
__device__ __forceinline__ void kmerge(unsigned long long& a, unsigned long long b) {
  if (b > a) a = b;
}
__device__ __forceinline__ unsigned long long kmax(unsigned long long a, unsigned long long b) {
  return b > a ? b : a;
}

// ---------------- prep: WfT[c][o] = Wf[o][c] --------------------------------
__global__ __launch_bounds__(256) void prep_wft(const float* __restrict__ Wf,
                                                float* __restrict__ WfT) {
  int t = blockIdx.x * 256 + threadIdx.x;
  if (t < 64 * 64) WfT[t] = Wf[(t & 63) * 64 + (t >> 6)];
}

// ---------------- prep: W1 -> MFMA A-fragment-ordered bf16 hi/lo ------------
__global__ __launch_bounds__(256) void prep_w1frag(const float* __restrict__ W1,
                                                   unsigned short* __restrict__ w1hi,
                                                   unsigned short* __restrict__ w1lo) {
  int t = blockIdx.x * 256 + threadIdx.x;
  if (t >= 8192) return;
  int j = t & 7, lane = (t >> 3) & 63, mt = (t >> 9) & 7, kt = t >> 12;
  int row = mt * 16 + (lane & 15);
  int k = kt * 32 + (lane >> 4) * 8 + j;
  float v = W1[row * 64 + k];
  unsigned short hi = f2bf(v);
  w1hi[t] = hi;
  w1lo[t] = f2bf(v - bf2f(hi));
}

// ---------------- fused fps (blocks 0-31) + rff (blocks 32-2079) ------------
// Shared-mem union: fps needs 64K P4 + 4K pick + 256B slots; rff needs 16.6K.
__device__ void fps_body(char* smem, const float* __restrict__ xyz,
                         float* __restrict__ out_xyz, int bt) {
  float4* P4 = (float4*)smem;                                      // 64 KB
  int* pick_l = (int*)(smem + 65536);                              // 4 KB
  unsigned long long* wslot = (unsigned long long*)(smem + 65536 + 4096);  // 2*16 u64
  const float* p = xyz + (size_t)bt * N * 3;
  int tid = threadIdx.x;
  int lane = tid & 63, w = tid >> 6;
  for (int i = tid; i < N; i += 256)
    P4[i] = make_float4(p[i * 3 + 0], p[i * 3 + 1], p[i * 3 + 2], 0.f);
  if (tid == 0) pick_l[0] = 0;
  __syncthreads();
  float X[16], Y[16], Z[16], D[16];
  unsigned inv[16];
#pragma unroll
  for (int j = 0; j < 16; ++j) {
    float4 v = P4[j * 256 + tid];  // consecutive lanes -> consecutive banks
    X[j] = v.x; Y[j] = v.y; Z[j] = v.z;
    D[j] = 1e10f;
    inv[j] = ~(unsigned)(j * 256 + tid);
  }
  int lidx = 0;
  for (int s = 1; s < M; ++s) {
    float4 lp = P4[lidx];  // broadcast ds_read_b128
    unsigned long long k[16];
#pragma unroll
    for (int j = 0; j < 16; ++j) {
      float dx = __fsub_rn(X[j], lp.x);
      float dy = __fsub_rn(Y[j], lp.y);
      float dz = __fsub_rn(Z[j], lp.z);
      float d = __fadd_rn(__fadd_rn(__fmul_rn(dx, dx), __fmul_rn(dy, dy)), __fmul_rn(dz, dz));
      float nd = fminf(D[j], d);
      D[j] = nd;
      k[j] = ((unsigned long long)__float_as_uint(nd) << 32) | inv[j];
    }
#pragma unroll
    for (int st = 8; st >= 1; st >>= 1)
#pragma unroll
      for (int j = 0; j < st; ++j) kmerge(k[j], k[j + st]);
    unsigned long long best = k[0];
    kmerge(best, dppu64<0xB1>(best));
    kmerge(best, dppu64<0x4E>(best));
    kmerge(best, dppu64<0x141>(best));
    kmerge(best, dppu64<0x140>(best));
    int buf = s & 1;
    if ((lane & 15) == 0) wslot[buf * 16 + w * 4 + (lane >> 4)] = best;
    __syncthreads();
    const ulonglong2* ws2 = (const ulonglong2*)&wslot[buf * 16];
    ulonglong2 a0 = ws2[0], a1 = ws2[1], a2 = ws2[2], a3 = ws2[3];
    ulonglong2 a4 = ws2[4], a5 = ws2[5], a6 = ws2[6], a7 = ws2[7];
    unsigned long long t0 = kmax(kmax(a0.x, a0.y), kmax(a1.x, a1.y));
    unsigned long long t1 = kmax(kmax(a2.x, a2.y), kmax(a3.x, a3.y));
    unsigned long long t2 = kmax(kmax(a4.x, a4.y), kmax(a5.x, a5.y));
    unsigned long long t3 = kmax(kmax(a6.x, a6.y), kmax(a7.x, a7.y));
    unsigned long long g = kmax(kmax(t0, t1), kmax(t2, t3));
    lidx = (int)(~(unsigned)g);
    if (tid == 0) pick_l[s] = lidx;
  }
  __syncthreads();
  float* outp = out_xyz + (size_t)bt * M * 3;
  for (int mm = tid; mm < M; mm += 256) {
    float4 v = P4[pick_l[mm]];
    outp[mm * 3 + 0] = v.x;
    outp[mm * 3 + 1] = v.y;
    outp[mm * 3 + 2] = v.z;
  }
}

__device__ void rff_body(char* smem, const float* __restrict__ f,
                         const float* __restrict__ WfT, float* __restrict__ RFF, int rid) {
  float (*tile)[65] = (float (*)[65])smem;  // 64x65 f32 = 16.6 KB
  int bt = rid >> 6;
  int n0 = (rid & 63) * 64;
  const float* src = f + (size_t)bt * C0 * N;
  int tx = threadIdx.x & 63, ty = threadIdx.x >> 6;
  for (int r = ty; r < 64; r += 4)
    tile[r][tx] = src[(size_t)r * N + n0 + tx];
  __syncthreads();
  float acc[16];
#pragma unroll
  for (int oo = 0; oo < 16; ++oo) acc[oo] = 0.f;
  int obase = ty * 16;
#pragma unroll 4
  for (int c = 0; c < 64; ++c) {
    float fv = tile[c][tx];
    const float* wr = WfT + c * 64 + obase;
#pragma unroll
    for (int oo = 0; oo < 16; ++oo) acc[oo] = fmaf(fv, wr[oo], acc[oo]);
  }
  __syncthreads();
#pragma unroll
  for (int oo = 0; oo < 16; ++oo) tile[obase + oo][tx] = fmaxf(acc[oo], 0.f);
  __syncthreads();
  float* dst = RFF + ((size_t)bt * N + n0) * 64;
  for (int r = ty; r < 64; r += 4)
    dst[(size_t)r * 64 + tx] = tile[tx][r];
}

__global__ __launch_bounds__(256) void fps_rff_kernel(const float* __restrict__ xyz,
                                                      float* __restrict__ out_xyz,
                                                      const float* __restrict__ feats,
                                                      const float* __restrict__ WfT,
                                                      float* __restrict__ RFF) {
  __shared__ __align__(16) char smem[65536 + 4096 + 256];
  if (blockIdx.x < 32)
    fps_body(smem, xyz, out_xyz, blockIdx.x);
  else
    rff_body(smem, feats, WfT, RFF, blockIdx.x - 32);
}

// ---------------- ball query: one wave per (b,t,di,m) -----------------------
__global__ __launch_bounds__(256) void ballq_kernel(const float* __restrict__ xyz,
                                                    const float* __restrict__ anchors,
                                                    int* __restrict__ idxbuf) {
  const float R2 = 0.04f;
  int w = threadIdx.x >> 6, lane = threadIdx.x & 63;
  int q = blockIdx.x * 4 + w;
  int m = q & (M - 1);
  int di = (q >> 10) % 3;
  int bt = q / (M * 3);
  int b = bt >> 3, t = bt & 7;
  int srct = t + di - 1;
  srct = srct < 0 ? 0 : (srct > 7 ? 7 : srct);
  const float* anc = anchors + ((size_t)(bt * M + m)) * 3;
  float ax = anc[0], ay = anc[1], az = anc[2];
  const float* pts = xyz + ((size_t)(b * T + srct)) * N * 3;
  int* outp = idxbuf + (size_t)q * KNN;
  int cnt = 0, first = 0;
  for (int c = 0; c < N / 64 && cnt < KNN; ++c) {
    int pi = c * 64 + lane;
    const float* pp = pts + (size_t)pi * 3;
    float dx = __fsub_rn(ax, pp[0]);
    float dy = __fsub_rn(ay, pp[1]);
    float dz = __fsub_rn(az, pp[2]);
    float d2 = __fadd_rn(__fadd_rn(__fmul_rn(dx, dx), __fmul_rn(dy, dy)), __fmul_rn(dz, dz));
    bool hit = d2 < R2;
    unsigned long long mask = __ballot(hit);
    if (cnt == 0 && mask) first = c * 64 + (int)__builtin_ctzll(mask);
    int prefix = (int)__popcll(mask & ((1ull << lane) - 1ull));
    int slot = cnt + prefix;
    if (hit && slot < KNN) outp[slot] = pi;
    cnt += (int)__popcll(mask);
  }
  int cntK = cnt < KNN ? cnt : KNN;
  int fill = (cnt == 0) ? 0 : first;
  if (lane < KNN && lane >= cntK) outp[lane] = fill;
}

// ---------------- fused gather + dfeat + split-bf16 MFMA layer2 (v3) --------
// wave = anchor; register-lean: no software prefetch, mt processed in two
// halves (c[4][2]), Wd reads hoisted per kt. Target <=160 VGPR, no scratch.
__global__ __launch_bounds__(256) void mlp_kernel(const float* __restrict__ xyz,
                                                  const float* __restrict__ RFF,
                                                  const unsigned short* __restrict__ w1hi,
                                                  const unsigned short* __restrict__ w1lo,
                                                  const float* __restrict__ Wd,
                                                  const float* __restrict__ anchors,
                                                  const int* __restrict__ idxbuf,
                                                  float* __restrict__ out_feats) {
  __shared__ unsigned short Ah[8192];
  __shared__ unsigned short Al[8192];
  __shared__ float wd_l[256];
  __shared__ float fstage[4][128];
  int tid = threadIdx.x;
  {
    uint4* dh = (uint4*)Ah;
    const uint4* sh = (const uint4*)w1hi;
    uint4* dl = (uint4*)Al;
    const uint4* sl = (const uint4*)w1lo;
    for (int i = tid; i < 1024; i += 256) { dh[i] = sh[i]; dl[i] = sl[i]; }
    wd_l[tid] = Wd[tid];
  }
  __syncthreads();
  int w = tid >> 6, lane = tid & 63;
  int nloc = lane & 15, grp = lane >> 4;
  int bt = blockIdx.x >> 8;
  int m0 = (blockIdx.x & 255) * 4;
  int m = m0 + w;
  int b = bt >> 3, t = bt & 7;
  int aoff = __builtin_amdgcn_readfirstlane(bt * M + m);
  float ax = anchors[(size_t)aoff * 3 + 0];
  float ay = anchors[(size_t)aoff * 3 + 1];
  float az = anchors[(size_t)aoff * 3 + 2];
  f32x4 acc[8];
#pragma unroll
  for (int mt = 0; mt < 8; ++mt) acc[mt] = (f32x4){0.f, 0.f, 0.f, 0.f};

  for (int di = 0; di < 3; ++di) {
    int srct = t + di - 1;
    srct = srct < 0 ? 0 : (srct > 7 ? 7 : srct);
    const float* rf = RFF + ((size_t)(b * T + srct)) * N * 64;
    const float* pts = xyz + ((size_t)(b * T + srct)) * N * 3;
    const int* ip = idxbuf + ((size_t)((bt * 3 + di) * M + m)) * KNN;
    int n0 = ip[nloc], n1 = ip[16 + nloc];
    float4 g0[2][2], g1[2][2];  // [kt][half] transient
#pragma unroll
    for (int kt = 0; kt < 2; ++kt) {
      const float* r0 = rf + (size_t)n0 * 64 + kt * 32 + grp * 8;
      const float* r1 = rf + (size_t)n1 * 64 + kt * 32 + grp * 8;
      g0[kt][0] = *(const float4*)&r0[0];
      g0[kt][1] = *(const float4*)&r0[4];
      g1[kt][0] = *(const float4*)&r1[0];
      g1[kt][1] = *(const float4*)&r1[4];
    }
    float dx0 = pts[n0 * 3 + 0] - ax, dy0 = pts[n0 * 3 + 1] - ay, dz0 = pts[n0 * 3 + 2] - az;
    float dx1 = pts[n1 * 3 + 0] - ax, dy1 = pts[n1 * 3 + 1] - ay, dz1 = pts[n1 * 3 + 2] - az;
    float tv = (float)(di - 1);
    short8 Bh[2][2], Bl[2][2];  // [kt][nt]
#pragma unroll
    for (int kt = 0; kt < 2; ++kt) {
      short8 bh0, bl0, bh1, bl1;
#pragma unroll
      for (int j = 0; j < 8; ++j) {
        int ch = kt * 32 + grp * 8 + j;
        float4 wr = *(const float4*)&wd_l[ch * 4];
        float dd0 = fmaf(dx0, wr.x, fmaf(dy0, wr.y, fmaf(dz0, wr.z, tv * wr.w)));
        float dd1 = fmaf(dx1, wr.x, fmaf(dy1, wr.y, fmaf(dz1, wr.z, tv * wr.w)));
        const float* gp0 = (const float*)&g0[kt][j >> 2];
        const float* gp1 = (const float*)&g1[kt][j >> 2];
        float h0 = gp0[j & 3] + fmaxf(dd0, 0.f);
        float h1 = gp1[j & 3] + fmaxf(dd1, 0.f);
        unsigned short hi0 = f2bf(h0);
        bh0[j] = (short)hi0;
        bl0[j] = (short)f2bf(h0 - bf2f(hi0));
        unsigned short hi1 = f2bf(h1);
        bh1[j] = (short)hi1;
        bl1[j] = (short)f2bf(h1 - bf2f(hi1));
      }
      Bh[kt][0] = bh0; Bl[kt][0] = bl0;
      Bh[kt][1] = bh1; Bl[kt][1] = bl1;
    }
#pragma unroll
    for (int hf = 0; hf < 2; ++hf) {
      f32x4 c[4][2];
#pragma unroll
      for (int mq = 0; mq < 4; ++mq) {
        c[mq][0] = (f32x4){0.f, 0.f, 0.f, 0.f};
        c[mq][1] = (f32x4){0.f, 0.f, 0.f, 0.f};
      }
#pragma unroll
      for (int kt = 0; kt < 2; ++kt) {
#pragma unroll
        for (int mq = 0; mq < 4; ++mq) {
          int mt = hf * 4 + mq;
          int fo = ((kt * 8 + mt) * 64 + lane) * 8;
          short8 ahf = *(const short8*)&Ah[fo];
          short8 alf = *(const short8*)&Al[fo];
          c[mq][0] = __builtin_amdgcn_mfma_f32_16x16x32_bf16(ahf, Bh[kt][0], c[mq][0], 0, 0, 0);
          c[mq][0] = __builtin_amdgcn_mfma_f32_16x16x32_bf16(ahf, Bl[kt][0], c[mq][0], 0, 0, 0);
          c[mq][0] = __builtin_amdgcn_mfma_f32_16x16x32_bf16(alf, Bh[kt][0], c[mq][0], 0, 0, 0);
          c[mq][1] = __builtin_amdgcn_mfma_f32_16x16x32_bf16(ahf, Bh[kt][1], c[mq][1], 0, 0, 0);
          c[mq][1] = __builtin_amdgcn_mfma_f32_16x16x32_bf16(ahf, Bl[kt][1], c[mq][1], 0, 0, 0);
          c[mq][1] = __builtin_amdgcn_mfma_f32_16x16x32_bf16(alf, Bh[kt][1], c[mq][1], 0, 0, 0);
        }
      }
#pragma unroll
      for (int mq = 0; mq < 4; ++mq)
#pragma unroll
        for (int r = 0; r < 4; ++r) {
          float o = fmaxf(c[mq][0][r], c[mq][1][r]);
          o = fmaxf(o, dppf<0xB1>(o));
          o = fmaxf(o, dppf<0x4E>(o));
          o = fmaxf(o, dppf<0x141>(o));
          o = fmaxf(o, dppf<0x140>(o));
          acc[hf * 4 + mq][r] += fmaxf(o, 0.f);
        }
    }
  }
  if (nloc == 0) {
#pragma unroll
    for (int mt = 0; mt < 8; ++mt)
#pragma unroll
      for (int r = 0; r < 4; ++r)
        fstage[w][mt * 16 + grp * 4 + r] = acc[mt][r];
  }
  __syncthreads();
  if (tid < 128) {
    float4 v = make_float4(fstage[0][tid], fstage[1][tid], fstage[2][tid], fstage[3][tid]);
    *(float4*)&out_feats[((size_t)(bt * C1 + tid)) * M + m0] = v;
  }
}

extern "C" void kernel_launch(void* const* d_in, const int* in_sizes, int n_in,
                              void* d_out, int out_size, void* d_ws, size_t ws_size,
                              hipStream_t stream) {
  const float* xyzs = (const float*)d_in[0];
  const float* feats = (const float*)d_in[1];
  const float* Wd = (const float*)d_in[2];
  const float* Wf = (const float*)d_in[3];
  const float* W1 = (const float*)d_in[4];
  float* out_xyz = (float*)d_out;                            // (B,8,M,3)
  float* out_feats = (float*)d_out + (size_t)B * T * M * 3;  // (B,8,C1,M)
  char* ws = (char*)d_ws;
  float* RFF = (float*)ws;                                          // 33.55 MB
  int* idxbuf = (int*)(ws + (size_t)B * T * N * 64 * 4);            // 12.58 MB
  char* tail = ws + (size_t)B * T * N * 64 * 4 + (size_t)B * T * 3 * M * KNN * 4;
  float* WfT = (float*)tail;                                        // 16 KB
  unsigned short* w1hi = (unsigned short*)(tail + 16384);           // 16 KB
  unsigned short* w1lo = (unsigned short*)(tail + 32768);           // 16 KB
  prep_wft<<<16, 256, 0, stream>>>(Wf, WfT);
  prep_w1frag<<<32, 256, 0, stream>>>(W1, w1hi, w1lo);
  fps_rff_kernel<<<32 + 2048, 256, 0, stream>>>(xyzs, out_xyz, feats, WfT, RFF);
  ballq_kernel<<<(B * T * 3 * M) / 4, 256, 0, stream>>>(xyzs, out_xyz, idxbuf);
  mlp_kernel<<<(B * T * M) / 4, 256, 0, stream>>>(xyzs, RFF, w1hi, w1lo, Wd, out_xyz,
                                                  idxbuf, out_feats);
}